// Round 1
// baseline (208.031 us; speedup 1.0000x reference)
//
#include <hip/hip_runtime.h>

#define OH 532
#define OW 532
#define PW_ 536
#define HW (536*536)
#define PDIM 75

// One block per (t*3+c) channel: mean of normalized noisy = 2*mean(noisy)-1
__global__ void means_kernel(const float* __restrict__ noisy,
                             float* __restrict__ means) {
    int ch = blockIdx.x;  // 0..5
    const float4* src = (const float4*)(noisy + (size_t)ch * OH * OW);
    const int n4 = OH * OW / 4;  // 283024/4 = 70756
    float s = 0.f;
    for (int i = threadIdx.x; i < n4; i += blockDim.x) {
        float4 v = src[i];
        s += v.x + v.y + v.z + v.w;
    }
    __shared__ float red[256];
    red[threadIdx.x] = s;
    __syncthreads();
    for (int off = 128; off > 0; off >>= 1) {
        if (threadIdx.x < off) red[threadIdx.x] += red[threadIdx.x + off];
        __syncthreads();
    }
    if (threadIdx.x == 0) {
        float mean = red[0] / (float)(OH * OW);
        means[ch] = 2.f * mean - 1.f;
    }
}

// One thread per output pixel (t,y,x); computes all 3 channels.
__global__ void fold_kernel(const float* __restrict__ deno,
                            const float* __restrict__ pw,
                            const float* __restrict__ means,
                            float* __restrict__ out) {
    int id = blockIdx.x * blockDim.x + threadIdx.x;
    if (id >= 2 * OH * OW) return;
    int x = id % OW;
    int y = (id / OW) % OH;
    int t = id / (OH * OW);

    const float* dn  = deno + (size_t)t * HW * PDIM;
    const float* wpt = pw   + (size_t)t * HW;

    float a0 = 0.f, a1 = 0.f, a2 = 0.f, wsum = 0.f;
    const int pbase = (y + 4) * PW_ + (x + 4);

#pragma unroll
    for (int i = 0; i < 5; ++i) {
#pragma unroll
        for (int j = 0; j < 5; ++j) {
            int p = pbase - i * PW_ - j;
            float w = wpt[p];
            const float* dp = dn + (size_t)p * PDIM + i * 5 + j;
            a0 += dp[0]  * w;
            a1 += dp[25] * w;
            a2 += dp[50] * w;
            wsum += w;
        }
    }

    float inv = 0.5f / wsum;  // folds the final *0.5 into the divide
    float m0 = means[t * 3 + 0] * 0.5f + 0.5f;
    float m1 = means[t * 3 + 1] * 0.5f + 0.5f;
    float m2 = means[t * 3 + 2] * 0.5f + 0.5f;

    size_t obase = ((size_t)(t * 3) * OH + y) * OW + x;
    out[obase]                       = a0 * inv + m0;
    out[obase + (size_t)OH * OW]     = a1 * inv + m1;
    out[obase + (size_t)2 * OH * OW] = a2 * inv + m2;
}

extern "C" void kernel_launch(void* const* d_in, const int* in_sizes, int n_in,
                              void* d_out, int out_size, void* d_ws, size_t ws_size,
                              hipStream_t stream) {
    const float* noisy = (const float*)d_in[0];
    const float* deno  = (const float*)d_in[1];
    const float* pw    = (const float*)d_in[2];
    // d_in[3] (inds) unused by the reference.
    float* out   = (float*)d_out;
    float* means = (float*)d_ws;  // 6 floats

    means_kernel<<<6, 256, 0, stream>>>(noisy, means);

    const int total = 2 * OH * OW;
    const int block = 256;
    const int grid = (total + block - 1) / block;
    fold_kernel<<<grid, block, 0, stream>>>(deno, pw, means, out);
}

// Round 2
// 133.539 us; speedup vs baseline: 1.5578x; 1.5578x over previous
//
#include <hip/hip_runtime.h>

#define OH 532
#define OW 532
#define PWID 536
#define HW (536*536)
#define NREC 75
#define TW 16
#define TH 16
#define FR (TH+4)        // footprint rows = 20
#define FC (TW+4)        // footprint cols = 20
#define ROWF (FC*NREC)   // 1500 floats per staged patch-row
#define SMEM_FLOATS (FR*ROWF + FR*FC)   // 30000 + 400
#define SMEM_BYTES (SMEM_FLOATS*4)      // 121600

// ---- means: partial sums (grid 64 x 6) ----
__global__ void means_part(const float* __restrict__ noisy, float* __restrict__ part) {
    int ch = blockIdx.y;
    int b  = blockIdx.x;
    const float4* src = (const float4*)(noisy + (size_t)ch * OH * OW);
    const int n4 = OH * OW / 4;           // 70756
    const int chunk = (n4 + 63) / 64;     // 1106
    int beg = b * chunk;
    int end = min(beg + chunk, n4);
    float s = 0.f;
    for (int i = beg + threadIdx.x; i < end; i += blockDim.x) {
        float4 v = src[i];
        s += v.x + v.y + v.z + v.w;
    }
    __shared__ float red[256];
    red[threadIdx.x] = s;
    __syncthreads();
    for (int off = 128; off > 0; off >>= 1) {
        if (threadIdx.x < off) red[threadIdx.x] += red[threadIdx.x + off];
        __syncthreads();
    }
    if (threadIdx.x == 0) part[ch * 64 + b] = red[0];
}

// ---- means: finalize (1 block, 384 threads = 6 waves, wave w = channel w) ----
__global__ void means_final(const float* __restrict__ part, float* __restrict__ means) {
    int w = threadIdx.x >> 6;
    int lane = threadIdx.x & 63;
    float s = part[w * 64 + lane];
    for (int off = 32; off > 0; off >>= 1) s += __shfl_down(s, off, 64);
    if (lane == 0) {
        float mean = s / (float)(OH * OW);
        means[w] = 2.f * mean - 1.f;   // normalized mean
    }
}

// ---- fold: LDS-staged 16x16 output tile ----
__global__ void fold_tile(const float* __restrict__ deno,
                          const float* __restrict__ pw,
                          const float* __restrict__ means,
                          float* __restrict__ out) {
    extern __shared__ float smem[];
    float* lds  = smem;             // [FR][ROWF] raw image of patch records
    float* ldsw = smem + FR * ROWF; // [FR][FC] patch weights

    const int t  = blockIdx.z;
    const int x0 = blockIdx.x * TW;   // multiple of 16 -> 16B-aligned rows
    const int y0 = blockIdx.y * TH;
    const int tid = threadIdx.x;

    const int rows = min(FR, PWID - y0);
    const int cols = min(FC, PWID - x0);

    const float* dbase = deno + (size_t)t * HW * NREC;
    const float* wbase = pw   + (size_t)t * HW;

    // stage records: per patch-row, cols*75 contiguous floats
    const int rowFloats = cols * NREC;
    const int row4 = rowFloats >> 2;
    const int tail = rowFloats & 3;
    for (int r = 0; r < rows; ++r) {
        const float* src = dbase + ((size_t)(y0 + r) * PWID + x0) * NREC;
        const float4* s4 = (const float4*)src;
        float4* d4 = (float4*)(lds + r * ROWF);
        for (int k = tid; k < row4; k += 256) d4[k] = s4[k];
        if (tid < tail) lds[r * ROWF + row4 * 4 + tid] = src[row4 * 4 + tid];
    }
    // stage weights
    for (int k = tid; k < rows * cols; k += 256) {
        int pr = k / cols, pc = k - pr * cols;
        ldsw[pr * FC + pc] = wbase[(size_t)(y0 + pr) * PWID + x0 + pc];
    }
    __syncthreads();

    const int tx = tid & (TW - 1);
    const int ty = tid >> 4;
    const int x = x0 + tx;
    const int y = y0 + ty;
    if (x >= OW || y >= OH) return;

    float a0 = 0.f, a1 = 0.f, a2 = 0.f, ws = 0.f;
#pragma unroll
    for (int pr = 0; pr < 5; ++pr) {
#pragma unroll
        for (int pc = 0; pc < 5; ++pc) {
            const int rr = ty + pr;          // local patch row (i = 4-pr)
            const int cc = tx + pc;          // local patch col (j = 4-pc)
            const float w = ldsw[rr * FC + cc];
            const float* rec = &lds[rr * ROWF + cc * NREC + (4 - pr) * 5 + (4 - pc)];
            a0 += rec[0]  * w;
            a1 += rec[25] * w;
            a2 += rec[50] * w;
            ws += w;
        }
    }

    const float inv = 0.5f / ws;
    const float m0 = means[t * 3 + 0] * 0.5f + 0.5f;
    const float m1 = means[t * 3 + 1] * 0.5f + 0.5f;
    const float m2 = means[t * 3 + 2] * 0.5f + 0.5f;

    const size_t obase = ((size_t)(t * 3) * OH + y) * OW + x;
    out[obase]                   = a0 * inv + m0;
    out[obase + (size_t)OH * OW] = a1 * inv + m1;
    out[obase + 2*(size_t)OH*OW] = a2 * inv + m2;
}

extern "C" void kernel_launch(void* const* d_in, const int* in_sizes, int n_in,
                              void* d_out, int out_size, void* d_ws, size_t ws_size,
                              hipStream_t stream) {
    const float* noisy = (const float*)d_in[0];
    const float* deno  = (const float*)d_in[1];
    const float* pw    = (const float*)d_in[2];
    // d_in[3] (inds) unused by the reference.
    float* out = (float*)d_out;

    float* part  = (float*)d_ws;        // 384 floats
    float* means = (float*)d_ws + 384;  // 6 floats

    // allow >64KB dynamic LDS (no-op if already set; host-side, capture-safe)
    hipFuncSetAttribute(reinterpret_cast<const void*>(&fold_tile),
                        hipFuncAttributeMaxDynamicSharedMemorySize, SMEM_BYTES);

    means_part<<<dim3(64, 6), 256, 0, stream>>>(noisy, part);
    means_final<<<1, 384, 0, stream>>>(part, means);

    dim3 grid((OW + TW - 1) / TW, (OH + TH - 1) / TH, 2);  // 34 x 34 x 2
    fold_tile<<<grid, 256, SMEM_BYTES, stream>>>(deno, pw, means, out);
}

// Round 3
// 59.662 us; speedup vs baseline: 3.4868x; 2.2383x over previous
//
#include <hip/hip_runtime.h>

#define OH 532
#define OW 532
#define PWID 536
#define HW (PWID*PWID)
#define NREC 75

// ---------------- means ----------------
__global__ void means_part(const float* __restrict__ noisy, float* __restrict__ part) {
    int ch = blockIdx.y;
    int b  = blockIdx.x;
    const float4* src = (const float4*)(noisy + (size_t)ch * OH * OW);
    const int n4 = OH * OW / 4;
    const int chunk = (n4 + 63) / 64;
    int beg = b * chunk;
    int end = min(beg + chunk, n4);
    float s = 0.f;
    for (int i = beg + threadIdx.x; i < end; i += blockDim.x) {
        float4 v = src[i];
        s += v.x + v.y + v.z + v.w;
    }
    __shared__ float red[256];
    red[threadIdx.x] = s;
    __syncthreads();
    for (int off = 128; off > 0; off >>= 1) {
        if (threadIdx.x < off) red[threadIdx.x] += red[threadIdx.x + off];
        __syncthreads();
    }
    if (threadIdx.x == 0) part[ch * 64 + b] = red[0];
}

__global__ void means_final(const float* __restrict__ part, float* __restrict__ means) {
    int w = threadIdx.x >> 6;
    int lane = threadIdx.x & 63;
    float s = part[w * 64 + lane];
    for (int off = 32; off > 0; off >>= 1) s += __shfl_down(s, off, 64);
    if (lane == 0) means[w] = 2.f * (s / (float)(OH * OW)) - 1.f;
}

// ---------------- stage 1: horizontal fold -> 16 planes ----------------
#define TXW 128
#define SREC 136   // 4 halo + 128 + 4 halo

__global__ void fold_s1(const float* __restrict__ deno,
                        const float* __restrict__ pw,
                        float* __restrict__ colacc) {
    __shared__ float lds[SREC * NREC];
    __shared__ float ldsw[SREC];

    const int bx = blockIdx.x;       // 0..4
    const int py = blockIdx.y;       // 0..535
    const int t  = blockIdx.z;
    const int x0 = bx * TXW;
    const int b0 = x0 - 4;
    const int lo = b0 < 0 ? 0 : b0;                 // multiple of 4
    int hi = x0 + TXW + 4; if (hi > PWID) hi = PWID; // multiple of 4
    const int tid = threadIdx.x;

    // stage records [lo, hi): contiguous, 16B-aligned, length %4 == 0
    const float* src = deno + ((size_t)t * HW + (size_t)py * PWID + lo) * NREC;
    const float4* s4 = (const float4*)src;
    float4* d4 = (float4*)(lds + (lo - b0) * NREC);
    const int n4 = ((hi - lo) * NREC) >> 2;
    for (int k = tid; k < n4; k += 256) d4[k] = s4[k];

    const float* wsrc = pw + (size_t)t * HW + (size_t)py * PWID;
    for (int k = lo + tid; k < hi; k += 256) ldsw[k - b0] = wsrc[k];
    __syncthreads();

    const int lx = tid & 127;
    const int half = tid >> 7;        // wave-uniform
    const int X = x0 + lx;
    if (X >= PWID) return;

    float* cbase = colacc + (size_t)t * 16 * HW + (size_t)py * PWID + X;
#pragma unroll
    for (int k = 0; k < 8; ++k) {
        const int ci = half * 8 + k;
        float acc = 0.f;
        if (ci < 15) {
            const int c = ci / 5, i = ci % 5;
#pragma unroll
            for (int j = 0; j < 5; ++j) {
                const int lpx = lx + 4 - j;
                acc += lds[lpx * NREC + c * 25 + i * 5 + j] * ldsw[lpx];
            }
        } else {
#pragma unroll
            for (int j = 0; j < 5; ++j) acc += ldsw[lx + 4 - j];
        }
        cbase[(size_t)ci * HW] = acc;
    }
}

// ---------------- stage 2: vertical fold + finalize ----------------
__global__ void fold_s2(const float* __restrict__ colacc,
                        const float* __restrict__ means,
                        float* __restrict__ out) {
    int id = blockIdx.x * 256 + threadIdx.x;
    if (id >= 2 * OH * OW) return;
    int x = id % OW;
    int r = id / OW;
    int y = r % OH;
    int t = r / OH;

    const float* ca = colacc + (size_t)t * 16 * HW + (x + 4);
    float wsv = 0.f;
#pragma unroll
    for (int i = 0; i < 5; ++i) wsv += ca[(size_t)15 * HW + (size_t)(y + 4 - i) * PWID];
    const float inv = 0.5f / wsv;

    const size_t ob = ((size_t)t * 3 * OH + y) * OW + x;
#pragma unroll
    for (int c = 0; c < 3; ++c) {
        float s = 0.f;
#pragma unroll
        for (int i = 0; i < 5; ++i)
            s += ca[(size_t)(c * 5 + i) * HW + (size_t)(y + 4 - i) * PWID];
        out[ob + (size_t)c * OH * OW] = s * inv + means[t * 3 + c] * 0.5f + 0.5f;
    }
}

// ---------------- fallback (round-2 single-pass) ----------------
#define TW 16
#define TH 16
#define FR (TH+4)
#define FC (TW+4)
#define ROWF (FC*NREC)
#define SMEM_BYTES ((FR*ROWF + FR*FC)*4)

__global__ void fold_tile(const float* __restrict__ deno,
                          const float* __restrict__ pw,
                          const float* __restrict__ means,
                          float* __restrict__ out) {
    extern __shared__ float smem[];
    float* lds  = smem;
    float* ldsw = smem + FR * ROWF;

    const int t  = blockIdx.z;
    const int x0 = blockIdx.x * TW;
    const int y0 = blockIdx.y * TH;
    const int tid = threadIdx.x;
    const int rows = min(FR, PWID - y0);
    const int cols = min(FC, PWID - x0);

    const float* dbase = deno + (size_t)t * HW * NREC;
    const float* wbase = pw   + (size_t)t * HW;

    const int rowFloats = cols * NREC;
    const int row4 = rowFloats >> 2;
    const int tail = rowFloats & 3;
    for (int r = 0; r < rows; ++r) {
        const float* src = dbase + ((size_t)(y0 + r) * PWID + x0) * NREC;
        const float4* s4 = (const float4*)src;
        float4* d4 = (float4*)(lds + r * ROWF);
        for (int k = tid; k < row4; k += 256) d4[k] = s4[k];
        if (tid < tail) lds[r * ROWF + row4 * 4 + tid] = src[row4 * 4 + tid];
    }
    for (int k = tid; k < rows * cols; k += 256) {
        int pr = k / cols, pc = k - pr * cols;
        ldsw[pr * FC + pc] = wbase[(size_t)(y0 + pr) * PWID + x0 + pc];
    }
    __syncthreads();

    const int tx = tid & (TW - 1);
    const int ty = tid >> 4;
    const int x = x0 + tx;
    const int y = y0 + ty;
    if (x >= OW || y >= OH) return;

    float a0 = 0.f, a1 = 0.f, a2 = 0.f, wsv = 0.f;
#pragma unroll
    for (int pr = 0; pr < 5; ++pr) {
#pragma unroll
        for (int pc = 0; pc < 5; ++pc) {
            const int rr = ty + pr;
            const int cc = tx + pc;
            const float w = ldsw[rr * FC + cc];
            const float* rec = &lds[rr * ROWF + cc * NREC + (4 - pr) * 5 + (4 - pc)];
            a0 += rec[0]  * w;
            a1 += rec[25] * w;
            a2 += rec[50] * w;
            wsv += w;
        }
    }
    const float inv = 0.5f / wsv;
    const size_t obase = ((size_t)(t * 3) * OH + y) * OW + x;
    out[obase]                   = a0 * inv + means[t*3+0]*0.5f + 0.5f;
    out[obase + (size_t)OH * OW] = a1 * inv + means[t*3+1]*0.5f + 0.5f;
    out[obase + 2*(size_t)OH*OW] = a2 * inv + means[t*3+2]*0.5f + 0.5f;
}

extern "C" void kernel_launch(void* const* d_in, const int* in_sizes, int n_in,
                              void* d_out, int out_size, void* d_ws, size_t ws_size,
                              hipStream_t stream) {
    const float* noisy = (const float*)d_in[0];
    const float* deno  = (const float*)d_in[1];
    const float* pw    = (const float*)d_in[2];
    float* out = (float*)d_out;

    float* part  = (float*)d_ws;        // 384
    float* means = (float*)d_ws + 384;  // 6
    float* colacc = (float*)d_ws + 512; // 16 planes x HW x 2t

    const size_t req = ((size_t)512 + (size_t)16 * HW * 2) * 4;

    means_part<<<dim3(64, 6), 256, 0, stream>>>(noisy, part);
    means_final<<<1, 384, 0, stream>>>(part, means);

    if (ws_size >= req) {
        fold_s1<<<dim3(5, PWID, 2), 256, 0, stream>>>(deno, pw, colacc);
        const int total = 2 * OH * OW;
        fold_s2<<<(total + 255) / 256, 256, 0, stream>>>(colacc, means, out);
    } else {
        hipFuncSetAttribute(reinterpret_cast<const void*>(&fold_tile),
                            hipFuncAttributeMaxDynamicSharedMemorySize, SMEM_BYTES);
        dim3 grid((OW + TW - 1) / TW, (OH + TH - 1) / TH, 2);
        fold_tile<<<grid, 256, SMEM_BYTES, stream>>>(deno, pw, means, out);
    }
}

// Round 4
// 55.517 us; speedup vs baseline: 3.7472x; 1.0747x over previous
//
#include <hip/hip_runtime.h>

#define OH 532
#define OW 532
#define PWID 536
#define HW (PWID*PWID)
#define NREC 75

typedef _Float16 half_t;

// ---------------- means ----------------
__global__ void means_part(const float* __restrict__ noisy, float* __restrict__ part) {
    int ch = blockIdx.y;
    int b  = blockIdx.x;
    const float4* src = (const float4*)(noisy + (size_t)ch * OH * OW);
    const int n4 = OH * OW / 4;
    const int chunk = (n4 + 63) / 64;
    int beg = b * chunk;
    int end = min(beg + chunk, n4);
    float s = 0.f;
    for (int i = beg + threadIdx.x; i < end; i += blockDim.x) {
        float4 v = src[i];
        s += v.x + v.y + v.z + v.w;
    }
    __shared__ float red[256];
    red[threadIdx.x] = s;
    __syncthreads();
    for (int off = 128; off > 0; off >>= 1) {
        if (threadIdx.x < off) red[threadIdx.x] += red[threadIdx.x + off];
        __syncthreads();
    }
    if (threadIdx.x == 0) part[ch * 64 + b] = red[0];
}

__global__ void means_final(const float* __restrict__ part, float* __restrict__ means) {
    int w = threadIdx.x >> 6;
    int lane = threadIdx.x & 63;
    float s = part[w * 64 + lane];
    for (int off = 32; off > 0; off >>= 1) s += __shfl_down(s, off, 64);
    if (lane == 0) means[w] = 2.f * (s / (float)(OH * OW)) - 1.f;
}

// ---------------- stage 1: horizontal fold -> 16 fp16 planes ----------------
#define TXW 128
#define SREC 136   // 4 halo + 128 + 4 halo

__global__ void fold_s1(const float* __restrict__ deno,
                        const float* __restrict__ pw,
                        half_t* __restrict__ colacc) {
    __shared__ float lds[SREC * NREC];
    __shared__ float ldsw[SREC];

    const int bx = blockIdx.x;       // 0..4
    const int py = blockIdx.y;       // 0..535
    const int t  = blockIdx.z;
    const int x0 = bx * TXW;
    const int b0 = x0 - 4;
    const int lo = b0 < 0 ? 0 : b0;                  // multiple of 4
    int hi = x0 + TXW + 4; if (hi > PWID) hi = PWID; // multiple of 4
    const int tid = threadIdx.x;

    // stage records [lo, hi): contiguous, 16B-aligned, length %4 == 0
    const float* src = deno + ((size_t)t * HW + (size_t)py * PWID + lo) * NREC;
    const float4* s4 = (const float4*)src;
    float4* d4 = (float4*)(lds + (lo - b0) * NREC);
    const int n4 = ((hi - lo) * NREC) >> 2;
    for (int k = tid; k < n4; k += 256) d4[k] = s4[k];

    const float* wsrc = pw + (size_t)t * HW + (size_t)py * PWID;
    for (int k = lo + tid; k < hi; k += 256) ldsw[k - b0] = wsrc[k];
    __syncthreads();

    const int lx = tid & 127;
    const int half = tid >> 7;        // wave-uniform
    const int X = x0 + lx;
    if (X >= PWID) return;

    half_t* cbase = colacc + (size_t)t * 16 * HW + (size_t)py * PWID + X;
#pragma unroll
    for (int k = 0; k < 8; ++k) {
        const int ci = half * 8 + k;
        float acc = 0.f;
        if (ci < 15) {
            const int c = ci / 5, i = ci % 5;
#pragma unroll
            for (int j = 0; j < 5; ++j) {
                const int lpx = lx + 4 - j;
                acc += lds[lpx * NREC + c * 25 + i * 5 + j] * ldsw[lpx];
            }
        } else {
#pragma unroll
            for (int j = 0; j < 5; ++j) acc += ldsw[lx + 4 - j];
        }
        cbase[(size_t)ci * HW] = (half_t)acc;
    }
}

// ---------------- stage 2: vertical fold + finalize (4 px/thread) ----------------
struct alignas(8) h4 { half_t a, b, c, d; };

__global__ void fold_s2(const half_t* __restrict__ colacc,
                        const float* __restrict__ means,
                        float* __restrict__ out) {
    const int NQ = OW / 4;   // 133
    int id = blockIdx.x * 256 + threadIdx.x;
    if (id >= 2 * OH * NQ) return;
    int xq = id % NQ;
    int y  = (id / NQ) % OH;
    int t  = id / (NQ * OH);
    int x = xq * 4;

    // base points at row (y+4), col (x+4); tap i reads row (y+4-i)
    const half_t* ca = colacc + (size_t)t * 16 * HW + (size_t)(y + 4) * PWID + (x + 4);

    float w0 = 0.f, w1 = 0.f, w2 = 0.f, w3 = 0.f;
#pragma unroll
    for (int i = 0; i < 5; ++i) {
        h4 v = *(const h4*)(ca + (size_t)15 * HW - (size_t)i * PWID);
        w0 += (float)v.a; w1 += (float)v.b; w2 += (float)v.c; w3 += (float)v.d;
    }
    const float i0 = 0.5f / w0, i1 = 0.5f / w1, i2 = 0.5f / w2, i3 = 0.5f / w3;

    const size_t ob = ((size_t)t * 3 * OH + y) * OW + x;
#pragma unroll
    for (int c = 0; c < 3; ++c) {
        float s0 = 0.f, s1 = 0.f, s2 = 0.f, s3 = 0.f;
#pragma unroll
        for (int i = 0; i < 5; ++i) {
            h4 v = *(const h4*)(ca + (size_t)(c * 5 + i) * HW - (size_t)i * PWID);
            s0 += (float)v.a; s1 += (float)v.b; s2 += (float)v.c; s3 += (float)v.d;
        }
        const float m = means[t * 3 + c] * 0.5f + 0.5f;
        float4 o;
        o.x = s0 * i0 + m; o.y = s1 * i1 + m; o.z = s2 * i2 + m; o.w = s3 * i3 + m;
        *(float4*)(out + ob + (size_t)c * OH * OW) = o;
    }
}

// ---------------- fallback (round-2 single-pass) ----------------
#define TW 16
#define TH 16
#define FR (TH+4)
#define FC (TW+4)
#define ROWF (FC*NREC)
#define SMEM_BYTES ((FR*ROWF + FR*FC)*4)

__global__ void fold_tile(const float* __restrict__ deno,
                          const float* __restrict__ pw,
                          const float* __restrict__ means,
                          float* __restrict__ out) {
    extern __shared__ float smem[];
    float* lds  = smem;
    float* ldsw = smem + FR * ROWF;

    const int t  = blockIdx.z;
    const int x0 = blockIdx.x * TW;
    const int y0 = blockIdx.y * TH;
    const int tid = threadIdx.x;
    const int rows = min(FR, PWID - y0);
    const int cols = min(FC, PWID - x0);

    const float* dbase = deno + (size_t)t * HW * NREC;
    const float* wbase = pw   + (size_t)t * HW;

    const int rowFloats = cols * NREC;
    const int row4 = rowFloats >> 2;
    const int tail = rowFloats & 3;
    for (int r = 0; r < rows; ++r) {
        const float* src = dbase + ((size_t)(y0 + r) * PWID + x0) * NREC;
        const float4* s4 = (const float4*)src;
        float4* d4 = (float4*)(lds + r * ROWF);
        for (int k = tid; k < row4; k += 256) d4[k] = s4[k];
        if (tid < tail) lds[r * ROWF + row4 * 4 + tid] = src[row4 * 4 + tid];
    }
    for (int k = tid; k < rows * cols; k += 256) {
        int pr = k / cols, pc = k - pr * cols;
        ldsw[pr * FC + pc] = wbase[(size_t)(y0 + pr) * PWID + x0 + pc];
    }
    __syncthreads();

    const int tx = tid & (TW - 1);
    const int ty = tid >> 4;
    const int x = x0 + tx;
    const int y = y0 + ty;
    if (x >= OW || y >= OH) return;

    float a0 = 0.f, a1 = 0.f, a2 = 0.f, wsv = 0.f;
#pragma unroll
    for (int pr = 0; pr < 5; ++pr) {
#pragma unroll
        for (int pc = 0; pc < 5; ++pc) {
            const int rr = ty + pr;
            const int cc = tx + pc;
            const float w = ldsw[rr * FC + cc];
            const float* rec = &lds[rr * ROWF + cc * NREC + (4 - pr) * 5 + (4 - pc)];
            a0 += rec[0]  * w;
            a1 += rec[25] * w;
            a2 += rec[50] * w;
            wsv += w;
        }
    }
    const float inv = 0.5f / wsv;
    const size_t obase = ((size_t)(t * 3) * OH + y) * OW + x;
    out[obase]                   = a0 * inv + means[t*3+0]*0.5f + 0.5f;
    out[obase + (size_t)OH * OW] = a1 * inv + means[t*3+1]*0.5f + 0.5f;
    out[obase + 2*(size_t)OH*OW] = a2 * inv + means[t*3+2]*0.5f + 0.5f;
}

extern "C" void kernel_launch(void* const* d_in, const int* in_sizes, int n_in,
                              void* d_out, int out_size, void* d_ws, size_t ws_size,
                              hipStream_t stream) {
    const float* noisy = (const float*)d_in[0];
    const float* deno  = (const float*)d_in[1];
    const float* pw    = (const float*)d_in[2];
    float* out = (float*)d_out;

    float* part  = (float*)d_ws;        // 384 floats
    float* means = (float*)d_ws + 384;  // 6 floats
    half_t* colacc = (half_t*)((char*)d_ws + 2048);  // 16 planes x HW x 2t, fp16

    const size_t req = 2048 + (size_t)16 * HW * 2 * sizeof(half_t);

    means_part<<<dim3(64, 6), 256, 0, stream>>>(noisy, part);
    means_final<<<1, 384, 0, stream>>>(part, means);

    if (ws_size >= req) {
        fold_s1<<<dim3(5, PWID, 2), 256, 0, stream>>>(deno, pw, colacc);
        const int NQ = OW / 4;
        const int total = 2 * OH * NQ;
        fold_s2<<<(total + 255) / 256, 256, 0, stream>>>(colacc, means, out);
    } else {
        hipFuncSetAttribute(reinterpret_cast<const void*>(&fold_tile),
                            hipFuncAttributeMaxDynamicSharedMemorySize, SMEM_BYTES);
        dim3 grid((OW + TW - 1) / TW, (OH + TH - 1) / TH, 2);
        fold_tile<<<grid, 256, SMEM_BYTES, stream>>>(deno, pw, means, out);
    }
}